// Round 1
// baseline (586.663 us; speedup 1.0000x reference)
//
#include <hip/hip_runtime.h>
#include <hip/hip_bf16.h>
#include <hip/hip_fp16.h>

// Problem constants: C=64, S=2048, H=512; rows = C*S = 131072
#define HDIM 512
#define NROWS 131072
#define NCAPS 64

typedef __attribute__((ext_vector_type(8))) short short8;
typedef __attribute__((ext_vector_type(4))) float floatx4;

__device__ __forceinline__ unsigned short f2bf(float f) {
  unsigned u = __float_as_uint(f);
  u += 0x7FFFu + ((u >> 16) & 1u);      // RTN-even
  return (unsigned short)(u >> 16);
}
__device__ __forceinline__ float bf2f(unsigned short h) {
  return __uint_as_float(((unsigned)h) << 16);
}

// ---------------------------------------------------------------------------
// Kernel 1: split W (fp32) into W_hi + W_lo bf16 pair (kills correlated-δW error)
// ---------------------------------------------------------------------------
__global__ __launch_bounds__(256) void prep_w_kernel(
    const float* __restrict__ W, unsigned short* __restrict__ wh,
    unsigned short* __restrict__ wl) {
  int i = (blockIdx.x * 256 + threadIdx.x) * 4;
  float4 f = *(const float4*)(W + i);
  float fv[4] = {f.x, f.y, f.z, f.w};
#pragma unroll
  for (int j = 0; j < 4; ++j) {
    unsigned short h = f2bf(fv[j]);
    wh[i + j] = h;
    wl[i + j] = f2bf(fv[j] - bf2f(h));
  }
}

// ---------------------------------------------------------------------------
// Kernel 2: GEMM  y[row][o] = sum_h x[row][h] * W[o][h] + bias[o]
//   - 128x128 tile, BK=64, 256 threads (4 waves, 2x2, each 64x64)
//   - 2 MFMAs per frag pair: a*wh + a*wl  (W-split)
//   - XOR-swizzled LDS chunk layout -> conflict-free ds_read_b128
//   - epilogue: store y fp16, atomicAdd per-row sum(y^2) into sq
// ---------------------------------------------------------------------------
#define BM 128
#define BN 128
#define BK 64

__global__ __launch_bounds__(256) void gemm_kernel(
    const float* __restrict__ x, const unsigned short* __restrict__ wh,
    const unsigned short* __restrict__ wl, const float* __restrict__ bias,
    __half* __restrict__ y, float* __restrict__ sq) {
  __shared__ unsigned short xs[BM * BK];
  __shared__ unsigned short whs[BN * BK];
  __shared__ unsigned short wls[BN * BK];

  const int tid = threadIdx.x;
  const int lane = tid & 63;
  const int widx = tid >> 6;
  const int wave_m = widx >> 1, wave_n = widx & 1;
  const int lrow = lane & 15, quad = lane >> 4, l7 = lane & 7;

  // grid swizzle: 4 n-blocks of one row-band land on the same XCD (bid%8) and
  // close in dispatch order -> x tile L2 reuse.
  const int bid = blockIdx.x;
  const int m_blk = ((bid >> 5) << 3) + (bid & 7);
  const int n_blk = (bid >> 3) & 3;
  const int row0 = m_blk * BM;
  const int col0 = n_blk * BN;

  floatx4 acc[4][4];
#pragma unroll
  for (int i = 0; i < 4; ++i)
#pragma unroll
    for (int j = 0; j < 4; ++j) acc[i][j] = (floatx4){0.f, 0.f, 0.f, 0.f};

  const int xm = tid >> 3;  // 0..31 (row within pass)
  const int xkg = tid & 7;  // 8-elem chunk
  const int wn_sub = lane >> 3;
  const int wphys = lane & 7;

  for (int kt = 0; kt < 8; ++kt) {
    const int k0 = kt * BK;
    __syncthreads();
    // ---- stage x: fp32 global -> bf16 LDS (swizzled) ----
#pragma unroll
    for (int p = 0; p < 4; ++p) {
      int m = p * 32 + xm;
      const float* gp = x + (size_t)(row0 + m) * HDIM + k0 + xkg * 8;
      float4 f0 = *(const float4*)gp;
      float4 f1 = *(const float4*)(gp + 4);
      short8 v;
      v[0] = (short)f2bf(f0.x); v[1] = (short)f2bf(f0.y);
      v[2] = (short)f2bf(f0.z); v[3] = (short)f2bf(f0.w);
      v[4] = (short)f2bf(f1.x); v[5] = (short)f2bf(f1.y);
      v[6] = (short)f2bf(f1.z); v[7] = (short)f2bf(f1.w);
      int phys = xkg ^ (m & 7);
      *(short8*)&xs[m * 64 + phys * 8] = v;
    }
    // ---- stage W hi/lo via global_load_lds width=16 (swizzled src addr) ----
#pragma unroll
    for (int q = 0; q < 4; ++q) {
      int i = widx * 4 + q;           // instr id 0..15, 8 rows each
      int n_loc = 8 * i + wn_sub;
      int kg_l = wphys ^ (n_loc & 7); // logical chunk that belongs at phys slot
      size_t goff = (size_t)(col0 + n_loc) * HDIM + k0 + kg_l * 8;
      __builtin_amdgcn_global_load_lds(
          (const __attribute__((address_space(1))) void*)(wh + goff),
          (__attribute__((address_space(3))) void*)&whs[i * 512], 16, 0, 0);
      __builtin_amdgcn_global_load_lds(
          (const __attribute__((address_space(1))) void*)(wl + goff),
          (__attribute__((address_space(3))) void*)&wls[i * 512], 16, 0, 0);
    }
    __syncthreads();
    // ---- compute: 2 k-steps of 32, 4x4 tiles, 2 MFMAs each ----
#pragma unroll
    for (int ks = 0; ks < 2; ++ks) {
      int physA = (ks * 4 + quad) ^ l7;
      short8 a[4], bh[4], bl[4];
#pragma unroll
      for (int mt = 0; mt < 4; ++mt) {
        int r = wave_m * 64 + mt * 16 + lrow;
        a[mt] = *(const short8*)&xs[r * 64 + physA * 8];
      }
#pragma unroll
      for (int nt = 0; nt < 4; ++nt) {
        int c = wave_n * 64 + nt * 16 + lrow;
        bh[nt] = *(const short8*)&whs[c * 64 + physA * 8];
        bl[nt] = *(const short8*)&wls[c * 64 + physA * 8];
      }
#pragma unroll
      for (int mt = 0; mt < 4; ++mt)
#pragma unroll
        for (int nt = 0; nt < 4; ++nt) {
          acc[mt][nt] = __builtin_amdgcn_mfma_f32_16x16x32_bf16(
              a[mt], bh[nt], acc[mt][nt], 0, 0, 0);
          acc[mt][nt] = __builtin_amdgcn_mfma_f32_16x16x32_bf16(
              a[mt], bl[nt], acc[mt][nt], 0, 0, 0);
        }
    }
  }

  // ---- epilogue: +bias, store fp16 y, accumulate row sum(y^2) ----
  int colg[4];
  float bias_v[4];
#pragma unroll
  for (int nt = 0; nt < 4; ++nt) {
    colg[nt] = col0 + wave_n * 64 + nt * 16 + lrow;
    bias_v[nt] = bias[colg[nt]];
  }
#pragma unroll
  for (int mt = 0; mt < 4; ++mt) {
#pragma unroll
    for (int r = 0; r < 4; ++r) {
      int rowg = row0 + wave_m * 64 + mt * 16 + quad * 4 + r;
      float s = 0.f;
#pragma unroll
      for (int nt = 0; nt < 4; ++nt) {
        float yv = acc[mt][nt][r] + bias_v[nt];
        s += yv * yv;
        y[(size_t)rowg * HDIM + colg[nt]] = __float2half(yv);
      }
      s += __shfl_xor(s, 1, 64);
      s += __shfl_xor(s, 2, 64);
      s += __shfl_xor(s, 4, 64);
      s += __shfl_xor(s, 8, 64);
      if (lrow == 0) atomicAdd(&sq[rowg], s);
    }
  }
}

// ---------------------------------------------------------------------------
// Kernel 3: scale[r] = sq/((1+sq)*sqrt(sq+eps))  (combined squash scale)
// ---------------------------------------------------------------------------
__global__ __launch_bounds__(256) void scale_kernel(const float* __restrict__ sq,
                                                    float* __restrict__ scale) {
  int i = blockIdx.x * 256 + threadIdx.x;
  float s = sq[i];
  scale[i] = s / ((1.f + s) * sqrtf(s + 1e-7f));
}

// ---------------------------------------------------------------------------
// Kernel 4 (fused routing pass, 1 read of y per iteration):
//   per row s: dot = y_s . c_prev ; b[s] += scale[s]*dot ; w = exp(b[s])
//              u   += w*scale[s]*y_s ; den += w
// With c_prev == 0 this is exactly the uniform-softmax first iteration.
// One wave per 32 rows; u kept in registers (8 fp32/lane).
// ---------------------------------------------------------------------------
__global__ __launch_bounds__(256) void kbv_kernel(
    const __half* __restrict__ y, const float* __restrict__ scale,
    float* __restrict__ b, const float* __restrict__ c_buf,
    float* __restrict__ u_part, float* __restrict__ den_part) {
  const int wave_g = blockIdx.x * 4 + (threadIdx.x >> 6);
  const int lane = threadIdx.x & 63;
  const int cap = wave_g >> 6;    // 64 chunks per capsule
  const int chunk = wave_g & 63;
  const int r0 = cap * 2048 + chunk * 32;

  float c8[8];
  {
    const float4* cp = (const float4*)(c_buf + cap * HDIM + lane * 8);
    float4 ca = cp[0], cb = cp[1];
    c8[0] = ca.x; c8[1] = ca.y; c8[2] = ca.z; c8[3] = ca.w;
    c8[4] = cb.x; c8[5] = cb.y; c8[6] = cb.z; c8[7] = cb.w;
  }
  float u8[8] = {0, 0, 0, 0, 0, 0, 0, 0};
  float den = 0.f;

  union U { int4 v; __half h[8]; };
  U cur;
  cur.v = *(const int4*)(y + (size_t)r0 * HDIM + lane * 8);

  for (int i = 0; i < 32; ++i) {
    int r = r0 + i;
    U nxt;
    if (i < 31) nxt.v = *(const int4*)(y + (size_t)(r + 1) * HDIM + lane * 8);
    float f[8];
#pragma unroll
    for (int j = 0; j < 8; ++j) f[j] = __half2float(cur.h[j]);
    float dot = f[0] * c8[0] + f[1] * c8[1] + f[2] * c8[2] + f[3] * c8[3] +
                f[4] * c8[4] + f[5] * c8[5] + f[6] * c8[6] + f[7] * c8[7];
    dot += __shfl_xor(dot, 1, 64);
    dot += __shfl_xor(dot, 2, 64);
    dot += __shfl_xor(dot, 4, 64);
    dot += __shfl_xor(dot, 8, 64);
    dot += __shfl_xor(dot, 16, 64);
    dot += __shfl_xor(dot, 32, 64);
    float sc = scale[r];
    float bn = b[r] + sc * dot;
    if (lane == 0) b[r] = bn;
    float w = expf(bn);   // |b| <= ~1e-3, max-subtraction unnecessary
    den += w;
    float wsc = w * sc;
#pragma unroll
    for (int j = 0; j < 8; ++j) u8[j] += wsc * f[j];
    cur = nxt;
  }
  float* up = u_part + (size_t)(cap * 64 + chunk) * HDIM + lane * 8;
  *(float4*)up = (float4){u8[0], u8[1], u8[2], u8[3]};
  *(float4*)(up + 4) = (float4){u8[4], u8[5], u8[6], u8[7]};
  if (lane == 0) den_part[cap * 64 + chunk] = den;
}

// ---------------------------------------------------------------------------
// Kernel 5: per capsule: v = (sum_chunk u_part)/(sum den_part); c = squash(v)
// ---------------------------------------------------------------------------
__global__ __launch_bounds__(256) void kcsq_kernel(
    const float* __restrict__ u_part, const float* __restrict__ den_part,
    float* __restrict__ out) {
  const int cap = blockIdx.x;
  const int t = threadIdx.x;
  __shared__ float red[256];
  __shared__ float sden;

  float d = 0.f;
  if (t < 64) d = den_part[cap * 64 + t];
  red[t] = d;
  __syncthreads();
  if (t == 0) {
    float s = 0.f;
    for (int i = 0; i < 64; ++i) s += red[i];
    sden = s;
  }
  __syncthreads();
  const float den = sden;

  float v0 = 0.f, v1 = 0.f;
  for (int ch = 0; ch < 64; ++ch) {
    const float* up = u_part + (size_t)(cap * 64 + ch) * HDIM;
    v0 += up[t];
    v1 += up[t + 256];
  }
  v0 /= den;
  v1 /= den;

  red[t] = v0 * v0 + v1 * v1;
  __syncthreads();
  for (int s = 128; s > 0; s >>= 1) {
    if (t < s) red[t] += red[t + s];
    __syncthreads();
  }
  const float sqv = red[0];
  const float scv = sqv / ((1.f + sqv) * sqrtf(sqv + 1e-7f));
  out[cap * HDIM + t] = v0 * scv;
  out[cap * HDIM + t + 256] = v1 * scv;
}

// ---------------------------------------------------------------------------
extern "C" void kernel_launch(void* const* d_in, const int* in_sizes, int n_in,
                              void* d_out, int out_size, void* d_ws,
                              size_t ws_size, hipStream_t stream) {
  const float* x = (const float*)d_in[0];     // [131072,512]
  const float* W = (const float*)d_in[1];     // [512,512]
  const float* bias = (const float*)d_in[2];  // [512]
  float* out = (float*)d_out;                 // [64,512]
  char* ws = (char*)d_ws;

  // workspace layout (16B aligned everywhere)
  __half* y = (__half*)ws;                                   // 134217728 B
  float* sq = (float*)(ws + (size_t)134217728);              // 131072 f
  float* b = sq + 131072;                                    // 131072 f
  float* c_buf = b + 131072;                                 // 32768 f
  float* scale = c_buf + 32768;                              // 131072 f
  unsigned short* wh = (unsigned short*)(scale + 131072);    // 262144 u16
  unsigned short* wl = wh + 262144;                          // 262144 u16
  float* u_part = (float*)(wl + 262144);                     // 64*64*512 f
  float* den_part = u_part + (size_t)64 * 64 * 512;          // 4096 f

  // zero sq, b, c_buf (contiguous)
  hipMemsetAsync(sq, 0, (size_t)(131072 + 131072 + 32768) * sizeof(float),
                 stream);

  prep_w_kernel<<<256, 256, 0, stream>>>(W, wh, wl);
  gemm_kernel<<<4096, 256, 0, stream>>>(x, wh, wl, bias, y, sq);
  scale_kernel<<<512, 256, 0, stream>>>(sq, scale);

  for (int it = 0; it < 3; ++it) {
    kbv_kernel<<<1024, 256, 0, stream>>>(y, scale, b, c_buf, u_part, den_part);
    kcsq_kernel<<<64, 256, 0, stream>>>(u_part, den_part,
                                        (it == 2) ? out : c_buf);
  }
}

// Round 3
// 549.593 us; speedup vs baseline: 1.0674x; 1.0674x over previous
//
#include <hip/hip_runtime.h>
#include <hip/hip_fp16.h>

// Problem constants: C=64, S=2048, H=512; rows = C*S = 131072
#define HDIM 512

typedef __fp16 fp16x2 __attribute__((ext_vector_type(2)));
typedef _Float16 h8 __attribute__((ext_vector_type(8)));
typedef __attribute__((ext_vector_type(4))) float floatx4;

// ---------------------------------------------------------------------------
// Kernel 1: W fp32 -> fp16 (RTE). Correlated dW error -> ~3e-8 at output
// (squash double-damping), safe vs 2e-6 threshold.
// ---------------------------------------------------------------------------
__global__ __launch_bounds__(256) void prep_w_kernel(
    const float* __restrict__ W, _Float16* __restrict__ wf) {
  int i = (blockIdx.x * 256 + threadIdx.x) * 4;
  float4 f = *(const float4*)(W + i);
  wf[i + 0] = (_Float16)f.x;
  wf[i + 1] = (_Float16)f.y;
  wf[i + 2] = (_Float16)f.z;
  wf[i + 3] = (_Float16)f.w;
}

// ---------------------------------------------------------------------------
// Kernel 2: GEMM y[row][o] = sum_h x[row][h]*W[o][h] + bias[o], fp16 MFMA
//   - 128x128 tile, BK=64, 256 thr (2x2 waves, 64x64 each), single MFMA/frag
//   - x: fp32 global -> v_cvt_pkrtz -> fp16 LDS (XOR-swizzled chunks)
//   - W: global_load_lds width=16, swizzled source addressing
//   - epilogue: y fp16 store + per-row sum(y^2) atomics into sq
// ---------------------------------------------------------------------------
#define BM 128
#define BN 128
#define BK 64

__global__ __launch_bounds__(256) void gemm_kernel(
    const float* __restrict__ x, const _Float16* __restrict__ wf,
    const float* __restrict__ bias, __half* __restrict__ y,
    float* __restrict__ sq) {
  __shared__ _Float16 xs[BM * BK];
  __shared__ _Float16 wsm[BN * BK];

  const int tid = threadIdx.x;
  const int lane = tid & 63;
  const int widx = tid >> 6;
  const int wave_m = widx >> 1, wave_n = widx & 1;
  const int lrow = lane & 15, quad = lane >> 4, l7 = lane & 7;

  // grid swizzle: 4 n-blocks of a row-band share an XCD -> x L2 reuse
  const int bid = blockIdx.x;
  const int m_blk = ((bid >> 5) << 3) + (bid & 7);
  const int n_blk = (bid >> 3) & 3;
  const int row0 = m_blk * BM;
  const int col0 = n_blk * BN;

  floatx4 acc[4][4];
#pragma unroll
  for (int i = 0; i < 4; ++i)
#pragma unroll
    for (int j = 0; j < 4; ++j) acc[i][j] = (floatx4){0.f, 0.f, 0.f, 0.f};

  const int xm = tid >> 3;   // row-within-pass 0..31
  const int xkg = tid & 7;   // 8-elem chunk
  const int wn_sub = lane >> 3;
  const int wphys = lane & 7;

  for (int kt = 0; kt < 8; ++kt) {
    const int k0 = kt * BK;
    __syncthreads();
    // ---- stage x: fp32 -> fp16 via pkrtz, swizzled LDS ----
#pragma unroll
    for (int p = 0; p < 4; ++p) {
      int m = p * 32 + xm;
      const float* gp = x + (size_t)(row0 + m) * HDIM + k0 + xkg * 8;
      float4 f0 = *(const float4*)gp;
      float4 f1 = *(const float4*)(gp + 4);
      union { h8 v8; fp16x2 v2[4]; } u;
      u.v2[0] = __builtin_amdgcn_cvt_pkrtz(f0.x, f0.y);
      u.v2[1] = __builtin_amdgcn_cvt_pkrtz(f0.z, f0.w);
      u.v2[2] = __builtin_amdgcn_cvt_pkrtz(f1.x, f1.y);
      u.v2[3] = __builtin_amdgcn_cvt_pkrtz(f1.z, f1.w);
      int phys = xkg ^ (m & 7);
      *(h8*)&xs[m * 64 + phys * 8] = u.v8;
    }
    // ---- stage W via global_load_lds width=16 (swizzled src) ----
#pragma unroll
    for (int q = 0; q < 4; ++q) {
      int i = widx * 4 + q;            // instr id 0..15, 8 rows each
      int n_loc = 8 * i + wn_sub;
      int kg_l = wphys ^ (n_loc & 7);
      size_t goff = (size_t)(col0 + n_loc) * HDIM + k0 + kg_l * 8;
      __builtin_amdgcn_global_load_lds(
          (const __attribute__((address_space(1))) void*)(wf + goff),
          (__attribute__((address_space(3))) void*)&wsm[i * 512], 16, 0, 0);
    }
    __syncthreads();
    // ---- compute: 2 k-steps, 4x4 tile, 16 MFMA each ----
#pragma unroll
    for (int ks = 0; ks < 2; ++ks) {
      int physA = (ks * 4 + quad) ^ l7;
      h8 a[4], bh[4];
#pragma unroll
      for (int mt = 0; mt < 4; ++mt) {
        int r = wave_m * 64 + mt * 16 + lrow;
        a[mt] = *(const h8*)&xs[r * 64 + physA * 8];
      }
#pragma unroll
      for (int nt = 0; nt < 4; ++nt) {
        int c = wave_n * 64 + nt * 16 + lrow;
        bh[nt] = *(const h8*)&wsm[c * 64 + physA * 8];
      }
#pragma unroll
      for (int mt = 0; mt < 4; ++mt)
#pragma unroll
        for (int nt = 0; nt < 4; ++nt)
          acc[mt][nt] = __builtin_amdgcn_mfma_f32_16x16x32_f16(
              a[mt], bh[nt], acc[mt][nt], 0, 0, 0);
    }
  }

  // ---- epilogue ----
  int colg[4];
  float bias_v[4];
#pragma unroll
  for (int nt = 0; nt < 4; ++nt) {
    colg[nt] = col0 + wave_n * 64 + nt * 16 + lrow;
    bias_v[nt] = bias[colg[nt]];
  }
#pragma unroll
  for (int mt = 0; mt < 4; ++mt) {
#pragma unroll
    for (int r = 0; r < 4; ++r) {
      int rowg = row0 + wave_m * 64 + mt * 16 + quad * 4 + r;
      float s = 0.f;
#pragma unroll
      for (int nt = 0; nt < 4; ++nt) {
        float yv = acc[mt][nt][r] + bias_v[nt];
        s += yv * yv;
        y[(size_t)rowg * HDIM + colg[nt]] = __float2half(yv);
      }
      s += __shfl_xor(s, 1, 64);
      s += __shfl_xor(s, 2, 64);
      s += __shfl_xor(s, 4, 64);
      s += __shfl_xor(s, 8, 64);
      if (lrow == 0) atomicAdd(&sq[rowg], s);
    }
  }
}

// ---------------------------------------------------------------------------
// Kernel 3 (fused routing pass): per row s:
//   sc = sq/((1+sq)sqrt(sq+eps)); dot = y_s.c_prev; b += sc*dot; w = exp(b)
//   u += w*sc*y_s ; den += w       (c_prev==0 -> exact uniform 1st iteration)
// 32 rows/wave, 4-row-unrolled groups for ILP across the shuffle chains.
// ---------------------------------------------------------------------------
__global__ __launch_bounds__(256) void kbv_kernel(
    const __half* __restrict__ y, const float* __restrict__ sqbuf,
    float* __restrict__ b, const float* __restrict__ c_buf,
    float* __restrict__ u_part, float* __restrict__ den_part) {
  const int wave_g = blockIdx.x * 4 + (threadIdx.x >> 6);
  const int lane = threadIdx.x & 63;
  const int cap = wave_g >> 6;   // 64 chunks per capsule
  const int chunk = wave_g & 63;
  const int r0 = cap * 2048 + chunk * 32;

  float c8[8];
  {
    const float4* cp = (const float4*)(c_buf + cap * HDIM + lane * 8);
    float4 ca = cp[0], cb = cp[1];
    c8[0] = ca.x; c8[1] = ca.y; c8[2] = ca.z; c8[3] = ca.w;
    c8[4] = cb.x; c8[5] = cb.y; c8[6] = cb.z; c8[7] = cb.w;
  }
  float u8[8] = {0, 0, 0, 0, 0, 0, 0, 0};
  float den = 0.f;

  union U { int4 v; __half hh[8]; };
  U cur[4], nxt[4];
  const __half* yb = y + (size_t)r0 * HDIM + lane * 8;
#pragma unroll
  for (int j = 0; j < 4; ++j) cur[j].v = *(const int4*)(yb + (size_t)j * HDIM);

  for (int g = 0; g < 8; ++g) {
    const int rg = r0 + g * 4;
    if (g < 7) {
#pragma unroll
      for (int j = 0; j < 4; ++j)
        nxt[j].v = *(const int4*)(yb + (size_t)(g * 4 + 4 + j) * HDIM);
    }
    float sc[4], bv[4];
#pragma unroll
    for (int j = 0; j < 4; ++j) {
      float s = sqbuf[rg + j];
      sc[j] = s / ((1.f + s) * sqrtf(s + 1e-7f));
      bv[j] = b[rg + j];
    }
    float dot[4];
#pragma unroll
    for (int j = 0; j < 4; ++j) {
      float d = 0.f;
#pragma unroll
      for (int k = 0; k < 8; ++k) d += __half2float(cur[j].hh[k]) * c8[k];
      dot[j] = d;
    }
#pragma unroll
    for (int s = 1; s < 64; s <<= 1) {
#pragma unroll
      for (int j = 0; j < 4; ++j) dot[j] += __shfl_xor(dot[j], s, 64);
    }
#pragma unroll
    for (int j = 0; j < 4; ++j) {
      float bn = bv[j] + sc[j] * dot[j];
      if (lane == 0) b[rg + j] = bn;
      float w = __expf(bn);   // |b| <= ~1e-3: no max-subtraction needed
      den += w;
      float wsc = w * sc[j];
#pragma unroll
      for (int k = 0; k < 8; ++k) u8[k] += wsc * __half2float(cur[j].hh[k]);
    }
#pragma unroll
    for (int j = 0; j < 4; ++j) cur[j] = nxt[j];
  }
  float* up = u_part + (size_t)(cap * 64 + chunk) * HDIM + lane * 8;
  *(float4*)up = (float4){u8[0], u8[1], u8[2], u8[3]};
  *(float4*)(up + 4) = (float4){u8[4], u8[5], u8[6], u8[7]};
  if (lane == 0) den_part[cap * 64 + chunk] = den;
}

// ---------------------------------------------------------------------------
// Kernel 4: per capsule: v = (sum_chunk u_part)/(sum den_part); c = squash(v)
// 512 threads: one h per thread, parallel tree reductions.
// ---------------------------------------------------------------------------
__global__ __launch_bounds__(512) void kcsq_kernel(
    const float* __restrict__ u_part, const float* __restrict__ den_part,
    float* __restrict__ out) {
  const int cap = blockIdx.x;
  const int t = threadIdx.x;
  __shared__ float red[512];

  float d = (t < 64) ? den_part[cap * 64 + t] : 0.f;
  red[t] = d;
  __syncthreads();
  for (int s = 256; s > 0; s >>= 1) {
    if (t < s) red[t] += red[t + s];
    __syncthreads();
  }
  const float den = red[0];
  __syncthreads();

  float v = 0.f;
  const float* up = u_part + (size_t)cap * 64 * HDIM + t;
  for (int ch = 0; ch < 64; ++ch) v += up[ch * HDIM];
  v /= den;

  red[t] = v * v;
  __syncthreads();
  for (int s = 256; s > 0; s >>= 1) {
    if (t < s) red[t] += red[t + s];
    __syncthreads();
  }
  const float sqv = red[0];
  const float scv = sqv / ((1.f + sqv) * sqrtf(sqv + 1e-7f));
  out[cap * HDIM + t] = v * scv;
}

// ---------------------------------------------------------------------------
extern "C" void kernel_launch(void* const* d_in, const int* in_sizes, int n_in,
                              void* d_out, int out_size, void* d_ws,
                              size_t ws_size, hipStream_t stream) {
  const float* x = (const float*)d_in[0];     // [131072,512]
  const float* W = (const float*)d_in[1];     // [512,512]
  const float* bias = (const float*)d_in[2];  // [512]
  float* out = (float*)d_out;                 // [64,512]
  char* ws = (char*)d_ws;

  // workspace layout (16B aligned; total ~144.2 MB)
  __half* y = (__half*)ws;                               // 134217728 B
  float* sq = (float*)(ws + (size_t)134217728);          // 131072 f
  float* b = sq + 131072;                                // 131072 f
  float* c_buf = b + 131072;                             // 32768 f
  _Float16* wf = (_Float16*)(c_buf + 32768);             // 262144 h
  float* u_part = (float*)(wf + 262144);                 // 64*64*512 f
  float* den_part = u_part + (size_t)64 * 64 * 512;      // 4096 f

  // zero sq, b, c_buf (contiguous)
  (void)hipMemsetAsync(sq, 0,
                       (size_t)(131072 + 131072 + 32768) * sizeof(float),
                       stream);

  prep_w_kernel<<<256, 256, 0, stream>>>(W, wf);
  gemm_kernel<<<4096, 256, 0, stream>>>(x, wf, bias, y, sq);

  for (int it = 0; it < 3; ++it) {
    kbv_kernel<<<1024, 256, 0, stream>>>(y, sq, b, c_buf, u_part, den_part);
    kcsq_kernel<<<64, 512, 0, stream>>>(u_part, den_part,
                                        (it == 2) ? out : c_buf);
  }
}